// Round 4
// baseline (106.411 us; speedup 1.0000x reference)
//
#include <hip/hip_runtime.h>
#include <math.h>

#define THREADS 256
#define BPB 8      // bins per term1 group
#define PCH 16     // pixel chunks per term1 group
#define TMAXB 128  // k_tmax blocks -> TMAXB*4 wave partials

// ws layout (bytes), all written with plain stores (no init/memset needed):
//   0:    uint  counter            (zeroed by k_tmax)
//   256:  float pmax[TMAXB*4]      (per-wave target-max partials)
//   4096: float psum[G]            (term2 per-block sums)
//   8192: float pmin[nb*PCH]       (term1 per-(bin,chunk) partial: min(t^2-2bt), b^2 excluded)

__device__ __forceinline__ float wmaxAll(float v) {
  #pragma unroll
  for (int o = 32; o > 0; o >>= 1) v = fmaxf(v, __shfl_xor(v, o, 64));
  return v;
}
__device__ __forceinline__ float wminAll(float v) {
  #pragma unroll
  for (int o = 32; o > 0; o >>= 1) v = fminf(v, __shfl_xor(v, o, 64));
  return v;
}
__device__ __forceinline__ float wsumAll(float v) {
  #pragma unroll
  for (int o = 32; o > 0; o >>= 1) v += __shfl_xor(v, o, 64);
  return v;
}
__device__ __forceinline__ double wsumAllD(double v) {
  #pragma unroll
  for (int o = 32; o > 0; o >>= 1) v += __shfl_xor(v, o, 64);
  return v;
}

__global__ __launch_bounds__(THREADS) void k_tmax(const float4* __restrict__ t4, int n4,
                                                  const float* __restrict__ t, int n,
                                                  float* __restrict__ pmax,
                                                  unsigned int* __restrict__ counter) {
  float v = 0.0f;  // target > 0
  int idx = blockIdx.x * THREADS + threadIdx.x;
  int stride = gridDim.x * THREADS;
  for (int i = idx; i < n4; i += stride) {
    float4 a = t4[i];
    v = fmaxf(v, fmaxf(fmaxf(a.x, a.y), fmaxf(a.z, a.w)));
  }
  for (int i = n4 * 4 + idx; i < n; i += stride) v = fmaxf(v, t[i]);
  v = wmaxAll(v);
  int lane = threadIdx.x & 63, w = threadIdx.x >> 6;
  if (lane == 0) pmax[blockIdx.x * 4 + w] = v;
  if (idx == 0) *counter = 0u;  // ticket for k_main's last-block finalize
}

__global__ __launch_bounds__(THREADS) void k_main(const float4* __restrict__ t4, int n4,
                                                  const float* __restrict__ t, int n,
                                                  const float* __restrict__ bins, int nb,
                                                  const float* __restrict__ pmax,
                                                  float* __restrict__ psum,
                                                  float* __restrict__ pmin,
                                                  unsigned int* __restrict__ counter,
                                                  float* __restrict__ out, int G) {
  __shared__ float sb[1024], hb[1024];  // b_n^2, -2*b_n
  __shared__ float sm1[4 * BPB];
  __shared__ float ss[4];
  __shared__ double ds[4];
  __shared__ unsigned int ticket;

  const int tid = threadIdx.x;
  const int lane = tid & 63, w = tid >> 6;
  const int bid = blockIdx.x;

  // per-wave (no cross-wave sync needed): tmax from partials, bmax from bins
  float v = 0.0f;
  for (int i = lane; i < TMAXB * 4; i += 64) v = fmaxf(v, pmax[i]);
  const float it = 1.0f / wmaxAll(v);
  float bv = 0.0f;
  for (int i = lane; i < nb; i += 64) bv = fmaxf(bv, bins[i]);
  const float ib = 1.0f / wmaxAll(bv);

  // stage normalized-bin tables for term2
  for (int i = tid; i < nb && i < 1024; i += THREADS) {
    float b = bins[i] * ib;
    sb[i] = b * b;
    hb[i] = -(b + b);
  }
  __syncthreads();

  // ---- term2: one float4 per thread, min over bins ----
  float lsum = 0.0f;
  {
    int idx = bid * THREADS + tid;
    if (idx < n4) {
      float4 a = t4[idx];
      float t0 = a.x * it, t1 = a.y * it, t2 = a.z * it, t3 = a.w * it;
      float m0 = 1e30f, m1 = 1e30f, m2 = 1e30f, m3 = 1e30f;
      #pragma unroll 8
      for (int j = 0; j < nb; j++) {
        float s = sb[j], h = hb[j];
        m0 = fminf(m0, fmaf(h, t0, s));
        m1 = fminf(m1, fmaf(h, t1, s));
        m2 = fminf(m2, fmaf(h, t2, s));
        m3 = fminf(m3, fmaf(h, t3, s));
      }
      // (t-b)^2 = t^2 + (b^2 - 2bt); mins are finite here
      lsum = (fmaf(t0, t0, m0) + fmaf(t1, t1, m1)) + (fmaf(t2, t2, m2) + fmaf(t3, t3, m3));
    }
    // global scalar tail handled by block 0
    int ntail = n - n4 * 4;
    if (bid == 0 && tid < ntail) {
      float tv = t[n4 * 4 + tid] * it;
      float m = 1e30f;
      for (int j = 0; j < nb; j++) m = fminf(m, fmaf(hb[j], tv, sb[j]));
      lsum += fmaf(tv, tv, m);
    }
  }

  // ---- term1: bin-group g, pixel-chunk c ----
  const int g = bid / PCH, c = bid % PCH;
  const int base = g * BPB;
  float bn[BPB], mn[BPB];
  #pragma unroll
  for (int k = 0; k < BPB; k++) {
    int bi = base + k;
    bn[k] = (bi < nb) ? bins[bi] * ib : 3e30f;
    mn[k] = 1e30f;  // stores min over pixels of (t^2 - 2*b*t); b^2 added in finalize
  }
  {
    const int chunk = (n4 + PCH - 1) / PCH;
    const int lo = c * chunk;
    const int hi = (lo + chunk < n4) ? lo + chunk : n4;
    for (int i = lo + tid; i < hi; i += THREADS) {
      float4 a = t4[i];
      float t0 = a.x * it, t1 = a.y * it, t2 = a.z * it, t3 = a.w * it;
      float s0 = t0 * t0, s1 = t1 * t1, s2 = t2 * t2, s3 = t3 * t3;
      float h0 = -(t0 + t0), h1 = -(t1 + t1), h2 = -(t2 + t2), h3 = -(t3 + t3);
      #pragma unroll
      for (int k = 0; k < BPB; k++) {
        float b = bn[k];
        mn[k] = fminf(mn[k], fmaf(h0, b, s0));
        mn[k] = fminf(mn[k], fmaf(h1, b, s1));
        mn[k] = fminf(mn[k], fmaf(h2, b, s2));
        mn[k] = fminf(mn[k], fmaf(h3, b, s3));
      }
    }
    int ntail = n - n4 * 4;
    if (c == 0 && tid < ntail) {
      float tv = t[n4 * 4 + tid] * it;
      float s = tv * tv, h = -(tv + tv);
      #pragma unroll
      for (int k = 0; k < BPB; k++) mn[k] = fminf(mn[k], fmaf(h, bn[k], s));
    }
  }

  // ---- block-level reductions (one sync) ----
  #pragma unroll
  for (int k = 0; k < BPB; k++) {
    float m = wminAll(mn[k]);
    if (lane == 0) sm1[w * BPB + k] = m;
  }
  float s = wsumAll(lsum);
  if (lane == 0) ss[w] = s;
  __syncthreads();
  if (tid == 0) psum[bid] = (ss[0] + ss[1]) + (ss[2] + ss[3]);
  if (tid < BPB && base + tid < nb) {
    float m = fminf(fminf(sm1[tid], sm1[BPB + tid]),
                    fminf(sm1[2 * BPB + tid], sm1[3 * BPB + tid]));
    pmin[(base + tid) * PCH + c] = m;
  }

  // ---- last-block finalize (ticket pattern) ----
  __threadfence();  // release our psum/pmin stores (device scope)
  if (tid == 0) ticket = atomicAdd(counter, 1u);
  __syncthreads();
  if (ticket == (unsigned int)(G - 1)) {
    __threadfence();  // acquire others' stores
    double tsum = 0.0;
    for (int b = tid; b < nb; b += THREADS) {
      float m = 1e30f;
      #pragma unroll
      for (int cc = 0; cc < PCH; cc++) m = fminf(m, pmin[b * PCH + cc]);
      float bnv = bins[b] * ib;
      float val = fmaf(bnv, bnv, m);  // add back b^2
      tsum += (m < 1e30f) ? (double)val : 0.0;  // all-inf row -> 0 per reference
    }
    for (int i = tid; i < G; i += THREADS) tsum += (double)psum[i];
    tsum = wsumAllD(tsum);
    if (lane == 0) ds[w] = tsum;
    __syncthreads();
    if (tid == 0) out[0] = (float)(((ds[0] + ds[1]) + (ds[2] + ds[3])));
  }
}

extern "C" void kernel_launch(void* const* d_in, const int* in_sizes, int n_in,
                              void* d_out, int out_size, void* d_ws, size_t ws_size,
                              hipStream_t stream) {
  const float* target = (const float*)d_in[0];
  const float* bins = (const float*)d_in[1];
  const int n = in_sizes[0];   // 307200
  const int nb = in_sizes[1];  // 256
  float* out = (float*)d_out;

  unsigned int* counter = (unsigned int*)d_ws;
  float* pmax = (float*)((char*)d_ws + 256);
  float* psum = (float*)((char*)d_ws + 4096);
  float* pmin = (float*)((char*)d_ws + 8192);

  const int n4 = n / 4;
  const float4* t4 = (const float4*)target;

  k_tmax<<<TMAXB, THREADS, 0, stream>>>(t4, n4, target, n, pmax, counter);

  const int G = ((nb + BPB - 1) / BPB) * PCH;  // 32*16 = 512 blocks
  k_main<<<G, THREADS, 0, stream>>>(t4, n4, target, n, bins, nb, pmax, psum, pmin,
                                    counter, out, G);
}

// Round 5
// 76.187 us; speedup vs baseline: 1.3967x; 1.3967x over previous
//
#include <hip/hip_runtime.h>
#include <math.h>

#define THREADS 256
#define BPB 8      // bins per term1 group
#define PCH 16     // pixel chunks per term1 group
#define TMAXB 128  // k_tmax blocks -> TMAXB*4 wave partials

// ws layout (bytes):
//   0:    uint   counter          (init 0 by k_tmax block 0)
//   64:   float  bmax             (plain store by k_tmax block 0 wave 0)
//   256:  float  pmax[TMAXB*4]    (per-wave target-max partials, plain stores)
//   2560: double psumd[8] slots   (64B apart; init 0 by k_tmax; atomicAdd in k_main)
//   4096: uint   binmin[256]      (init 0xFFFFFFFF by k_tmax; atomicMin keys in k_main)

__device__ __forceinline__ float wmaxAll(float v) {
  #pragma unroll
  for (int o = 32; o > 0; o >>= 1) v = fmaxf(v, __shfl_xor(v, o, 64));
  return v;
}
__device__ __forceinline__ float wminAll(float v) {
  #pragma unroll
  for (int o = 32; o > 0; o >>= 1) v = fminf(v, __shfl_xor(v, o, 64));
  return v;
}
__device__ __forceinline__ float wsumAll(float v) {
  #pragma unroll
  for (int o = 32; o > 0; o >>= 1) v += __shfl_xor(v, o, 64);
  return v;
}
__device__ __forceinline__ double wsumAllD(double v) {
  #pragma unroll
  for (int o = 32; o > 0; o >>= 1) v += __shfl_xor(v, o, 64);
  return v;
}

// totally-ordered uint key for float (works for negatives too)
__device__ __forceinline__ unsigned keyEnc(float f) {
  unsigned u = __float_as_uint(f);
  return (u & 0x80000000u) ? ~u : (u | 0x80000000u);
}
__device__ __forceinline__ float keyDec(unsigned k) {
  unsigned u = (k & 0x80000000u) ? (k ^ 0x80000000u) : ~k;
  return __uint_as_float(u);
}

__global__ __launch_bounds__(THREADS) void k_tmax(const float4* __restrict__ t4, int n4,
                                                  const float* __restrict__ t, int n,
                                                  const float* __restrict__ bins, int nb,
                                                  float* __restrict__ pmax,
                                                  float* __restrict__ bmax,
                                                  unsigned int* __restrict__ counter,
                                                  double* __restrict__ psumd,
                                                  unsigned int* __restrict__ binmin) {
  const int tid = threadIdx.x;
  const int lane = tid & 63, w = tid >> 6;
  float v = 0.0f;  // target > 0
  int idx = blockIdx.x * THREADS + tid;
  int stride = gridDim.x * THREADS;
  for (int i = idx; i < n4; i += stride) {
    float4 a = t4[i];
    v = fmaxf(v, fmaxf(fmaxf(a.x, a.y), fmaxf(a.z, a.w)));
  }
  for (int i = n4 * 4 + idx; i < n; i += stride) v = fmaxf(v, t[i]);
  v = wmaxAll(v);
  if (lane == 0) pmax[blockIdx.x * 4 + w] = v;

  if (blockIdx.x == 0) {
    // init all atomic targets (plain stores; visible to next dispatch)
    for (int i = tid; i < 256; i += THREADS) binmin[i] = 0xFFFFFFFFu;
    if (tid < 8) psumd[tid * 8] = 0.0;
    if (tid == 0) *counter = 0u;
    // bins max (wave 0 only)
    if (w == 0) {
      float bv = 0.0f;
      for (int i = lane; i < nb; i += 64) bv = fmaxf(bv, bins[i]);
      bv = wmaxAll(bv);
      if (lane == 0) *bmax = bv;
    }
  }
}

// blocks [0, nt2):        term2 — one float4/thread, min over bins (LDS tables)
// blocks [nt2, nt2+nt1):  term1 — bin-group g, pixel-chunk c; atomicMin keys
// last block (ticket):    finalize — decode binmin + b^2, add psumd, write out
__global__ __launch_bounds__(THREADS) void k_main(const float4* __restrict__ t4, int n4,
                                                  const float* __restrict__ t, int n,
                                                  const float* __restrict__ bins, int nb,
                                                  const float* __restrict__ pmax,
                                                  const float* __restrict__ bmax,
                                                  double* __restrict__ psumd,
                                                  unsigned int* __restrict__ binmin,
                                                  unsigned int* __restrict__ counter,
                                                  float* __restrict__ out,
                                                  int nt2, int G) {
  __shared__ float sb[256], hb[256];  // b_n^2, -2*b_n
  __shared__ float sm1[4 * BPB];
  __shared__ float ss[4];
  __shared__ double ds[4];
  __shared__ unsigned int ticket;

  const int tid = threadIdx.x;
  const int lane = tid & 63, w = tid >> 6;
  const int bid = blockIdx.x;

  // per-wave reduce of target-max partials (coalesced, L2-hot) + bmax scalar
  float v = 0.0f;
  for (int i = lane; i < TMAXB * 4; i += 64) v = fmaxf(v, pmax[i]);
  const float it = 1.0f / wmaxAll(v);
  const float ib = 1.0f / *bmax;

  if (bid < nt2) {
    // ---- term2 ----
    for (int i = tid; i < nb && i < 256; i += THREADS) {
      float b = bins[i] * ib;
      sb[i] = b * b;
      hb[i] = -(b + b);
    }
    __syncthreads();
    float lsum = 0.0f;
    int idx = bid * THREADS + tid;
    if (idx < n4) {
      float4 a = t4[idx];
      float t0 = a.x * it, t1 = a.y * it, t2 = a.z * it, t3 = a.w * it;
      float m0 = 1e30f, m1 = 1e30f, m2 = 1e30f, m3 = 1e30f;
      #pragma unroll 8
      for (int j = 0; j < nb; j++) {
        float s = sb[j], h = hb[j];
        m0 = fminf(m0, fmaf(h, t0, s));
        m1 = fminf(m1, fmaf(h, t1, s));
        m2 = fminf(m2, fmaf(h, t2, s));
        m3 = fminf(m3, fmaf(h, t3, s));
      }
      lsum = (fmaf(t0, t0, m0) + fmaf(t1, t1, m1)) + (fmaf(t2, t2, m2) + fmaf(t3, t3, m3));
    }
    int ntail = n - n4 * 4;
    if (bid == 0 && tid < ntail) {
      float tv = t[n4 * 4 + tid] * it;
      float m = 1e30f;
      for (int j = 0; j < nb; j++) m = fminf(m, fmaf(hb[j], tv, sb[j]));
      lsum += fmaf(tv, tv, m);
    }
    float s = wsumAll(lsum);
    if (lane == 0) ss[w] = s;
    __syncthreads();
    if (tid == 0)
      atomicAdd(&psumd[(bid & 7) * 8], (double)((ss[0] + ss[1]) + (ss[2] + ss[3])));
  } else {
    // ---- term1 ----
    const int b1 = bid - nt2;
    const int g = b1 / PCH, c = b1 % PCH;
    const int base = g * BPB;
    float bn[BPB], mn[BPB];
    #pragma unroll
    for (int k = 0; k < BPB; k++) {
      int bi = base + k;
      bn[k] = (bi < nb) ? bins[bi] * ib : 3e30f;
      mn[k] = 1e30f;  // min over pixels of (t^2 - 2*b*t); b^2 added in finalize
    }
    const int chunk = (n4 + PCH - 1) / PCH;
    const int lo = c * chunk;
    const int hi = (lo + chunk < n4) ? lo + chunk : n4;
    for (int i = lo + tid; i < hi; i += THREADS) {
      float4 a = t4[i];
      float t0 = a.x * it, t1 = a.y * it, t2 = a.z * it, t3 = a.w * it;
      float s0 = t0 * t0, s1 = t1 * t1, s2 = t2 * t2, s3 = t3 * t3;
      float h0 = -(t0 + t0), h1 = -(t1 + t1), h2 = -(t2 + t2), h3 = -(t3 + t3);
      #pragma unroll
      for (int k = 0; k < BPB; k++) {
        float b = bn[k];
        mn[k] = fminf(mn[k], fmaf(h0, b, s0));
        mn[k] = fminf(mn[k], fmaf(h1, b, s1));
        mn[k] = fminf(mn[k], fmaf(h2, b, s2));
        mn[k] = fminf(mn[k], fmaf(h3, b, s3));
      }
    }
    int ntail = n - n4 * 4;
    if (c == 0 && tid < ntail) {
      float tv = t[n4 * 4 + tid] * it;
      float s = tv * tv, h = -(tv + tv);
      #pragma unroll
      for (int k = 0; k < BPB; k++) mn[k] = fminf(mn[k], fmaf(h, bn[k], s));
    }
    #pragma unroll
    for (int k = 0; k < BPB; k++) {
      float m = wminAll(mn[k]);
      if (lane == 0) sm1[w * BPB + k] = m;
    }
    __syncthreads();
    if (tid < BPB && base + tid < nb) {
      float m = fminf(fminf(sm1[tid], sm1[BPB + tid]),
                      fminf(sm1[2 * BPB + tid], sm1[3 * BPB + tid]));
      atomicMin(&binmin[base + tid], keyEnc(m));
    }
  }

  // ---- last-block finalize via ticket; atomics-only state, no cache fences ----
  asm volatile("s_waitcnt vmcnt(0)" ::: "memory");  // all our atomics acked
  if (tid == 0) ticket = atomicAdd(counter, 1u);
  __syncthreads();
  if (ticket == (unsigned int)(G - 1)) {
    double tsum = 0.0;
    for (int b = tid; b < nb; b += THREADS) {
      float m = keyDec(binmin[b]);             // min of (t^2 - 2bt) over all pixels
      float bnv = bins[b] * ib;
      float val = fmaf(bnv, bnv, m);           // add back b^2
      tsum += (m < 1e29f) ? (double)val : 0.0; // guards NaN/inf (comparison false)
    }
    if (tid < 8) tsum += psumd[tid * 8];
    tsum = wsumAllD(tsum);
    if (lane == 0) ds[w] = tsum;
    __syncthreads();
    if (tid == 0) out[0] = (float)((ds[0] + ds[1]) + (ds[2] + ds[3]));
  }
}

extern "C" void kernel_launch(void* const* d_in, const int* in_sizes, int n_in,
                              void* d_out, int out_size, void* d_ws, size_t ws_size,
                              hipStream_t stream) {
  const float* target = (const float*)d_in[0];
  const float* bins = (const float*)d_in[1];
  const int n = in_sizes[0];   // 307200
  const int nb = in_sizes[1];  // 256
  float* out = (float*)d_out;

  unsigned int* counter = (unsigned int*)d_ws;
  float* bmax = (float*)((char*)d_ws + 64);
  float* pmax = (float*)((char*)d_ws + 256);
  double* psumd = (double*)((char*)d_ws + 2560);
  unsigned int* binmin = (unsigned int*)((char*)d_ws + 4096);

  const int n4 = n / 4;
  const float4* t4 = (const float4*)target;

  k_tmax<<<TMAXB, THREADS, 0, stream>>>(t4, n4, target, n, bins, nb,
                                        pmax, bmax, counter, psumd, binmin);

  const int nt2 = (n4 + THREADS - 1) / THREADS;        // 300 term2 blocks
  const int nt1 = ((nb + BPB - 1) / BPB) * PCH;        // 512 term1 blocks
  const int G = nt2 + nt1;
  k_main<<<G, THREADS, 0, stream>>>(t4, n4, target, n, bins, nb, pmax, bmax,
                                    psumd, binmin, counter, out, nt2, G);
}